// Round 1
// baseline (38.324 us; speedup 1.0000x reference)
//
#include <hip/hip_runtime.h>

// YOLO v1 loss, forward only. preds/labels: [16384, 7, 7, 30] f32 -> scalar f32.
#define NCELLS (16384 * 7 * 7)   // 802816
#define THREADS 256
#define NBLOCKS ((NCELLS + THREADS - 1) / THREADS)  // 3136

__device__ __forceinline__ float iou_fn(const float* a, const float* b) {
    // boxes (cx, cy, w, h)
    float a_l = a[0] - a[2] * 0.5f, a_r = a[0] + a[2] * 0.5f;
    float a_t = a[1] - a[3] * 0.5f, a_b = a[1] + a[3] * 0.5f;
    float b_l = b[0] - b[2] * 0.5f, b_r = b[0] + b[2] * 0.5f;
    float b_t = b[1] - b[3] * 0.5f, b_b = b[1] + b[3] * 0.5f;
    float iw = fmaxf(fminf(a_r, b_r) - fmaxf(a_l, b_l), 0.0f);
    float ih = fmaxf(fminf(a_b, b_b) - fmaxf(a_t, b_t), 0.0f);
    float inter = iw * ih;
    float denom = a[2] * a[3] + b[2] * b[3] - inter + 1e-10f;
    return inter / denom;
}

__device__ __forceinline__ float block_reduce(float acc) {
    // wave (64-lane) shuffle reduce, then across the block's 4 waves via LDS.
    #pragma unroll
    for (int off = 32; off > 0; off >>= 1) acc += __shfl_down(acc, off);
    __shared__ float s[THREADS / 64];
    int lane = threadIdx.x & 63, wid = threadIdx.x >> 6;
    if (lane == 0) s[wid] = acc;
    __syncthreads();
    float r = 0.0f;
    if (threadIdx.x == 0) {
        #pragma unroll
        for (int w = 0; w < THREADS / 64; ++w) r += s[w];
    }
    return r;
}

__global__ __launch_bounds__(THREADS) void yolo_partial(
        const float* __restrict__ preds, const float* __restrict__ labels,
        float* __restrict__ partials) {
    int cell = blockIdx.x * THREADS + threadIdx.x;
    float loss = 0.0f;
    if (cell < NCELLS) {
        const float2* pp = (const float2*)(preds + (size_t)cell * 30);
        const float2* lp = (const float2*)(labels + (size_t)cell * 30);
        float p[30], l[30];
        #pragma unroll
        for (int i = 0; i < 15; ++i) {
            float2 v = pp[i]; p[2 * i] = v.x; p[2 * i + 1] = v.y;
        }
        #pragma unroll
        for (int i = 0; i < 15; ++i) {
            float2 v = lp[i]; l[2 * i] = v.x; l[2 * i + 1] = v.y;
        }

        float obj = l[4];
        float noobj = 1.0f - obj;
        float iou1 = iou_fn(p + 0, l + 0);
        float iou2 = iou_fn(p + 5, l + 0);
        bool r1 = iou1 > iou2;
        float rb0 = r1 ? p[0] : p[5];
        float rb1 = r1 ? p[1] : p[6];
        float rb2 = r1 ? p[2] : p[7];
        float rb3 = r1 ? p[3] : p[8];
        float rconf = r1 ? p[4] : p[9];
        float oconf = r1 ? p[9] : p[4];
        float riou = fmaxf(iou1, iou2);

        float dx = rb0 - l[0], dy = rb1 - l[1];
        float lxy = dx * dx + dy * dy;

        float spw = sqrtf(fmaxf(rb2, 1e-8f)), sgw = sqrtf(fmaxf(l[2], 1e-8f));
        float sph = sqrtf(fmaxf(rb3, 1e-8f)), sgh = sqrtf(fmaxf(l[3], 1e-8f));
        float dw = spw - sgw, dh = sph - sgh;
        float lwh = dw * dw + dh * dh;

        float dob = rconf - riou;

        float cls = 0.0f;
        #pragma unroll
        for (int c = 10; c < 30; ++c) {
            float d = p[c] - l[c];
            cls += d * d;
        }

        loss = obj * (5.0f * (lxy + lwh) + dob * dob + 0.5f * oconf * oconf + cls)
             + 0.5f * noobj * (p[4] * p[4] + p[9] * p[9]);
    }
    float r = block_reduce(loss);
    if (threadIdx.x == 0) partials[blockIdx.x] = r;
}

__global__ __launch_bounds__(THREADS) void yolo_final(
        const float* __restrict__ partials, float* __restrict__ out) {
    float acc = 0.0f;
    for (int i = threadIdx.x; i < NBLOCKS; i += THREADS) acc += partials[i];
    float r = block_reduce(acc);
    if (threadIdx.x == 0) out[0] = r * (1.0f / 16384.0f);
}

extern "C" void kernel_launch(void* const* d_in, const int* in_sizes, int n_in,
                              void* d_out, int out_size, void* d_ws, size_t ws_size,
                              hipStream_t stream) {
    const float* preds  = (const float*)d_in[0];
    const float* labels = (const float*)d_in[1];
    float* out = (float*)d_out;
    float* partials = (float*)d_ws;   // NBLOCKS * 4 bytes = 12.5 KB

    yolo_partial<<<NBLOCKS, THREADS, 0, stream>>>(preds, labels, partials);
    yolo_final<<<1, THREADS, 0, stream>>>(partials, out);
}